// Round 11
// baseline (291.438 us; speedup 1.0000x reference)
//
#include <hip/hip_runtime.h>
#include <hip/hip_bf16.h>

typedef __bf16 bf16_t;
typedef __bf16 bf16x8 __attribute__((ext_vector_type(8)));
typedef __bf16 bf16x4 __attribute__((ext_vector_type(4)));
typedef float f32x4 __attribute__((ext_vector_type(4)));

// LDS: bufA 32K | bufB 32K | rpbT 4K | cm bitmask 512B | pad mask 8B = 70152 B -> 2 blocks/CU
#define OFF_A   0
#define OFF_B   32768
#define OFF_RPB 65536
#define OFF_CMM (65536 + 4096)
#define OFF_PAD (65536 + 4096 + 512)
#define SMEM_BYTES (65536 + 4096 + 512 + 8)

// 64x256 bf16 tile, row stride 512B, XOR-swizzled 16B chunks.
// Per row r, wave w's 4 chunks form group (w ^ ((r>>2)&1)) -- disjoint across waves.
__device__ __forceinline__ int tile_off(int r, int c) {
  return (r << 9) + ((((c >> 3) ^ (r & 7)) << 4) | ((c & 7) << 1));
}
// 256x64 bf16 vt tile (row = feature d, col = token j), stride 128B
__device__ __forceinline__ int vt_off(int d, int j) {
  return (d << 7) + ((((j >> 3) ^ (d & 7)) << 4) | ((j & 7) << 1));
}
// P stored in wave's own k-chunk area of bufB: row i, 32-j half, chunk t = jl>>3
__device__ __forceinline__ int pk_off(int wv, int i, int t, int byteoff) {
  return (i << 9) + ((((wv << 2) + t) ^ (i & 7)) << 4) + byteoff;
}

template <int UNROLL>
__device__ __forceinline__ void stage_x(const float* __restrict__ src, char* __restrict__ dst, int tid) {
  const float4* s4 = (const float4*)src;
#pragma unroll
  for (int kk = 0; kk < 8; kk += UNROLL) {
    float4 v[UNROLL];
#pragma unroll
    for (int u = 0; u < UNROLL; ++u) v[u] = s4[tid + ((kk + u) << 9)];
#pragma unroll
    for (int u = 0; u < UNROLL; ++u) {
      int f = tid + ((kk + u) << 9);
      int row = f >> 6;
      int col = (f & 63) << 2;
      bf16x4 p;
      p[0] = (bf16_t)v[u].x; p[1] = (bf16_t)v[u].y; p[2] = (bf16_t)v[u].z; p[3] = (bf16_t)v[u].w;
      *(bf16x4*)(dst + tile_off(row, col)) = p;
    }
  }
}

// y[0:64, cb:cb+32] = A(64x256 swizzled LDS) @ W(256x256 bf16 row-major)^T
__device__ __forceinline__ void gemm_tile(const char* __restrict__ sA, const bf16_t* __restrict__ W,
                                          int cb, int l15, int g, f32x4 acc[4][2]) {
#pragma unroll
  for (int kt = 0; kt < 8; ++kt) {
    bf16x8 a[4];
#pragma unroll
    for (int mt = 0; mt < 4; ++mt)
      a[mt] = *(const bf16x8*)(sA + tile_off(mt*16 + l15, kt*32 + g*8));
#pragma unroll
    for (int nt = 0; nt < 2; ++nt) {
      bf16x8 bw = *(const bf16x8*)(W + (cb + nt*16 + l15)*256 + kt*32 + g*8);
#pragma unroll
      for (int mt = 0; mt < 4; ++mt)
        acc[mt][nt] = __builtin_amdgcn_mfma_f32_16x16x32_bf16(a[mt], bw, acc[mt][nt], 0, 0, 0);
    }
  }
}

__global__ __launch_bounds__(512)
__attribute__((amdgpu_waves_per_eu(4, 4)))   // 128-total budget; arch liveness now targeted <=64
void chunk_attn_kernel(
    const float* __restrict__ qg, const float* __restrict__ kg, const float* __restrict__ vg,
    const float* __restrict__ maskg, const float* __restrict__ cmg,
    const float* __restrict__ bq, const float* __restrict__ bk, const float* __restrict__ bv,
    const float* __restrict__ bo, const float* __restrict__ rpbg,
    const bf16_t* __restrict__ Wb, float* __restrict__ outg) {
  extern __shared__ char sm[];
  char*  bufA  = sm + OFF_A;
  char*  bufB  = sm + OFF_B;
  float* sRpb  = (float*)(sm + OFF_RPB);    // transposed: [head][128] floats
  char*  sCmm  = sm + OFF_CMM;              // 64 x u64 row bitmasks (bit j: cm[i][j] == -100)

  const int b = blockIdx.x, tid = threadIdx.x;
  const int wave = tid >> 6, lane = tid & 63, l15 = lane & 15, g = lane >> 4;
  const int cb = wave << 5;             // head h = wave, feature base h*32

  for (int i = tid; i < 1016; i += 512) sRpb[((i & 7) << 7) + (i >> 3)] = rpbg[i];
  { // pad-mask bits (wave 0) + chunk-mask bits (all waves, 8 rows each) via ballot
    if (wave == 0) {
      float mv = maskg[(b << 6) + lane];
      unsigned long long bm = __ballot(mv == 0.0f);
      if (lane == 0) *(unsigned long long*)(sm + OFF_PAD) = bm;
    }
    const float* cmb = cmg + ((size_t)(b & 127) << 12);
#pragma unroll
    for (int it = 0; it < 8; ++it) {
      int row = (wave << 3) + it;
      float cv = cmb[(row << 6) + lane];
      unsigned long long bm = __ballot(cv < -50.0f);
      if (lane == 0) *(unsigned long long*)(sCmm + (row << 3)) = bm;
    }
  }
  stage_x<4>(qg + (size_t)b*16384, bufA, tid);
  stage_x<4>(kg + (size_t)b*16384, bufB, tid);
  __syncthreads();                                        // B1

  { // q projection -> bufA
    f32x4 acc[4][2] = {};
    gemm_tile(bufA, Wb + 0*65536, cb, l15, g, acc);
    __syncthreads();                                      // B2a: X_q dead
    float b0 = bq[cb+l15], b1 = bq[cb+16+l15];
#pragma unroll
    for (int mt = 0; mt < 4; ++mt)
#pragma unroll
      for (int nt = 0; nt < 2; ++nt)
#pragma unroll
        for (int r = 0; r < 4; ++r)
          *(bf16_t*)(bufA + tile_off(mt*16 + g*4 + r, cb + nt*16 + l15)) =
              (bf16_t)(acc[mt][nt][r] + (nt ? b1 : b0));
  }
  { // k projection -> bufB
    f32x4 acc[4][2] = {};
    gemm_tile(bufB, Wb + 1*65536, cb, l15, g, acc);
    __syncthreads();                                      // B2b: X_k dead
    float b0 = bk[cb+l15], b1 = bk[cb+16+l15];
#pragma unroll
    for (int mt = 0; mt < 4; ++mt)
#pragma unroll
      for (int nt = 0; nt < 2; ++nt)
#pragma unroll
        for (int r = 0; r < 4; ++r)
          *(bf16_t*)(bufB + tile_off(mt*16 + g*4 + r, cb + nt*16 + l15)) =
              (bf16_t)(acc[mt][nt][r] + (nt ? b1 : b0));
  }
  __asm__ volatile("s_waitcnt lgkmcnt(0)" ::: "memory");  // wave-private q/k RAW

  // scores^T + masked softmax, two ni-halves
  const float* rpbw = sRpb + (wave << 7);
  unsigned long long padm = *(const unsigned long long*)(sm + OFF_PAD);
  unsigned int padl = (unsigned int)padm, padh = (unsigned int)(padm >> 32);
  float rinv[4];
  bf16x4 pbf01[2][4];                    // P for j<32  (stored to LDS right after softmax)
  bf16x4 pbf23[2][4];                    // P for j>=32 (stored mid-PV)
#pragma unroll
  for (int half = 0; half < 2; ++half) {
    f32x4 Sh[4][2];                      // St[j][i] for this ni-half
    {
      bf16x8 qb0 = *(const bf16x8*)(bufA + tile_off((2*half + 0)*16 + l15, cb + g*8));
      bf16x8 qb1 = *(const bf16x8*)(bufA + tile_off((2*half + 1)*16 + l15, cb + g*8));
      const f32x4 z = {};
#pragma unroll
      for (int mj = 0; mj < 4; ++mj) {
        bf16x8 ka = *(const bf16x8*)(bufB + tile_off(mj*16 + l15, cb + g*8));
        Sh[mj][0] = __builtin_amdgcn_mfma_f32_16x16x32_bf16(ka, qb0, z, 0, 0, 0);
        Sh[mj][1] = __builtin_amdgcn_mfma_f32_16x16x32_bf16(ka, qb1, z, 0, 0, 0);
      }
    }
#pragma unroll
    for (int nih = 0; nih < 2; ++nih) {
      int ni = 2*half + nih;
      int i = ni*16 + l15;
      unsigned long long cmm = *(const unsigned long long*)(sCmm + (i << 3));
      unsigned int cml = (unsigned int)cmm, cmh = (unsigned int)(cmm >> 32);
      float m = -1e30f;
#pragma unroll
      for (int mj = 0; mj < 4; ++mj) {
        unsigned int cw = (mj >= 2) ? cmh : cml;
        unsigned int pw = (mj >= 2) ? padh : padl;
#pragma unroll
        for (int r = 0; r < 4; ++r) {
          int j = mj*16 + g*4 + r;
          int sh = j & 31;
          float s1 = Sh[mj][nih][r] * 0.17677669529663689f + rpbw[i - j + 63];
          float base = ((pw >> sh) & 1u) ? -100.0f : s1;
          float sc = ((cw >> sh) & 1u) ? base - 100.0f : base;
          Sh[mj][nih][r] = sc;
          m = fmaxf(m, sc);
        }
      }
      m = fmaxf(m, __shfl_xor(m, 16));
      m = fmaxf(m, __shfl_xor(m, 32));
      float s = 0.0f;
#pragma unroll
      for (int mj = 0; mj < 4; ++mj)
#pragma unroll
        for (int r = 0; r < 4; ++r) {
          float p = __expf(Sh[mj][nih][r] - m);
          if (mj < 2) pbf01[mj][ni][r] = (bf16_t)p;
          else        pbf23[mj-2][ni][r] = (bf16_t)p;
          s += p;
        }
      s += __shfl_xor(s, 16);
      s += __shfl_xor(s, 32);
      rinv[ni] = 1.0f / s;
    }
  }

  // store P(j<32) into wave's own k-chunk area of bufB (k dead for this wave; wave-private)
#pragma unroll
  for (int mj = 0; mj < 2; ++mj)
#pragma unroll
    for (int ni = 0; ni < 4; ++ni)
      *(bf16x4*)(bufB + pk_off(wave, ni*16 + l15, 2*mj + (g >> 1), (g & 1)*8)) = pbf01[mj][ni];

  __syncthreads();                                        // B3: q globally dead
  stage_x<2>(vg + (size_t)b*16384, bufA, tid);            // X_v -> bufA
  __syncthreads();                                        // B4

  f32x4 vacc[4][2] = {};
  gemm_tile(bufA, Wb + 2*65536, cb, l15, g, vacc);        // v-proj (reads bufA)
  __syncthreads();                                        // B4b: all X_v reads done
  { // vt -> bufA (rows [cb,cb+32), transposed: row=feat, col=token); wave-private
    float b0 = bv[cb+l15], b1 = bv[cb+16+l15];
#pragma unroll
    for (int nt = 0; nt < 2; ++nt)
#pragma unroll
      for (int mt = 0; mt < 4; ++mt) {
        bf16x4 p;
#pragma unroll
        for (int r = 0; r < 4; ++r) p[r] = (bf16_t)(vacc[mt][nt][r] + (nt ? b1 : b0));
        *(bf16x4*)(bufA + vt_off(cb + nt*16 + l15, mt*16 + g*4)) = p;
      }
  }
  __asm__ volatile("s_waitcnt lgkmcnt(0)" ::: "memory");  // vt + P RAW (both wave-private)

  // PV: x^T[d][i] = sum_j vt[d,j] P^T[j,i]; P halves from wave's k-area
  f32x4 Xa[2][4] = {};
  { // h2 = 0: j in [0,32)
    bf16x8 va0 = *(const bf16x8*)(bufA + vt_off(cb + l15,      g*8));
    bf16x8 va1 = *(const bf16x8*)(bufA + vt_off(cb + 16 + l15, g*8));
#pragma unroll
    for (int ni = 0; ni < 4; ++ni) {
      bf16x8 pb = *(const bf16x8*)(bufB + pk_off(wave, ni*16 + l15, g, 0));
      Xa[0][ni] = __builtin_amdgcn_mfma_f32_16x16x32_bf16(va0, pb, Xa[0][ni], 0, 0, 0);
      Xa[1][ni] = __builtin_amdgcn_mfma_f32_16x16x32_bf16(va1, pb, Xa[1][ni], 0, 0, 0);
    }
  }
  // store P(j>=32) over the same wave-private area, then second half
#pragma unroll
  for (int mj = 0; mj < 2; ++mj)
#pragma unroll
    for (int ni = 0; ni < 4; ++ni)
      *(bf16x4*)(bufB + pk_off(wave, ni*16 + l15, 2*mj + (g >> 1), (g & 1)*8)) = pbf23[mj][ni];
  __asm__ volatile("s_waitcnt lgkmcnt(0)" ::: "memory");
  { // h2 = 1: j in [32,64)
    bf16x8 va0 = *(const bf16x8*)(bufA + vt_off(cb + l15,      32 + g*8));
    bf16x8 va1 = *(const bf16x8*)(bufA + vt_off(cb + 16 + l15, 32 + g*8));
#pragma unroll
    for (int ni = 0; ni < 4; ++ni) {
      bf16x8 pb = *(const bf16x8*)(bufB + pk_off(wave, ni*16 + l15, g, 0));
      Xa[0][ni] = __builtin_amdgcn_mfma_f32_16x16x32_bf16(va0, pb, Xa[0][ni], 0, 0, 0);
      Xa[1][ni] = __builtin_amdgcn_mfma_f32_16x16x32_bf16(va1, pb, Xa[1][ni], 0, 0, 0);
    }
  }

  // x (normalized) -> wave's own chunk-columns of bufB (P dead for this wave)
#pragma unroll
  for (int mtd = 0; mtd < 2; ++mtd)
#pragma unroll
    for (int ni = 0; ni < 4; ++ni)
#pragma unroll
      for (int r = 0; r < 4; ++r)
        *(bf16_t*)(bufB + tile_off(ni*16 + l15, cb + mtd*16 + g*4 + r)) =
            (bf16_t)(Xa[mtd][ni][r] * rinv[ni]);
  __syncthreads();                                        // B7: all x written

  { // out = x @ Wo^T + bo
    f32x4 acc[4][2] = {};
    gemm_tile(bufB, Wb + 3*65536, cb, l15, g, acc);
    float b0 = bo[cb+l15], b1 = bo[cb+16+l15];
    float* ob = outg + (size_t)b * 16384;
#pragma unroll
    for (int mt = 0; mt < 4; ++mt)
#pragma unroll
      for (int nt = 0; nt < 2; ++nt)
#pragma unroll
        for (int r = 0; r < 4; ++r)
          ob[(mt*16 + g*4 + r)*256 + cb + nt*16 + l15] = acc[mt][nt][r] + (nt ? b1 : b0);
  }
}

__global__ void cvt_weights(const float* __restrict__ Wq, const float* __restrict__ Wk,
                            const float* __restrict__ Wv, const float* __restrict__ Wo,
                            bf16_t* __restrict__ dst) {
  int idx = blockIdx.x * 256 + threadIdx.x;
  int which = idx >> 14;
  int off = idx & 16383;
  const float* src = (which == 0) ? Wq : (which == 1) ? Wk : (which == 2) ? Wv : Wo;
  float4 v = ((const float4*)src)[off];
  bf16x4 p;
  p[0] = (bf16_t)v.x; p[1] = (bf16_t)v.y; p[2] = (bf16_t)v.z; p[3] = (bf16_t)v.w;
  *(bf16x4*)(dst + which*65536 + off*4) = p;
}

extern "C" void kernel_launch(void* const* d_in, const int* in_sizes, int n_in,
                              void* d_out, int out_size, void* d_ws, size_t ws_size,
                              hipStream_t stream) {
  (void)in_sizes; (void)n_in; (void)out_size; (void)ws_size;
  const float* qg  = (const float*)d_in[0];
  const float* kg  = (const float*)d_in[1];
  const float* vg  = (const float*)d_in[2];
  const float* mg  = (const float*)d_in[3];
  const float* cmg = (const float*)d_in[4];
  const float* Wq  = (const float*)d_in[5];
  const float* bq  = (const float*)d_in[6];
  const float* Wk  = (const float*)d_in[7];
  const float* bk  = (const float*)d_in[8];
  const float* Wv  = (const float*)d_in[9];
  const float* bv  = (const float*)d_in[10];
  const float* Wo  = (const float*)d_in[11];
  const float* bo  = (const float*)d_in[12];
  const float* rpb = (const float*)d_in[13];
  bf16_t* Wb = (bf16_t*)d_ws;           // 4 * 65536 bf16 = 512 KB
  float* outg = (float*)d_out;

  hipFuncSetAttribute(reinterpret_cast<const void*>(chunk_attn_kernel),
                      hipFuncAttributeMaxDynamicSharedMemorySize, SMEM_BYTES);
  cvt_weights<<<256, 256, 0, stream>>>(Wq, Wk, Wv, Wo, Wb);
  chunk_attn_kernel<<<2048, 512, SMEM_BYTES, stream>>>(qg, kg, vg, mg, cmg,
      bq, bk, bv, bo, rpb, Wb, outg);
}

// Round 12
// 251.824 us; speedup vs baseline: 1.1573x; 1.1573x over previous
//
#include <hip/hip_runtime.h>
#include <hip/hip_bf16.h>

typedef __bf16 bf16_t;
typedef __bf16 bf16x8 __attribute__((ext_vector_type(8)));
typedef __bf16 bf16x4 __attribute__((ext_vector_type(4)));
typedef float f32x4 __attribute__((ext_vector_type(4)));

// LDS: bufA 32K | bufB 32K | rpbT 4K | cm bitmask 512B | pad mask 8B = 70152 B
#define OFF_A   0
#define OFF_B   32768
#define OFF_RPB 65536
#define OFF_CMM (65536 + 4096)
#define OFF_PAD (65536 + 4096 + 512)
#define SMEM_BYTES (65536 + 4096 + 512 + 8)

// 64x256 bf16 tile, row stride 512B, XOR-swizzled 16B chunks
__device__ __forceinline__ int tile_off(int r, int c) {
  return (r << 9) + ((((c >> 3) ^ (r & 7)) << 4) | ((c & 7) << 1));
}
// 256x64 bf16 vt tile (row = feature d, col = token j), stride 128B
__device__ __forceinline__ int vt_off(int d, int j) {
  return (d << 7) + ((((j >> 3) ^ (d & 7)) << 4) | ((j & 7) << 1));
}
// per-wave P^T scratch: 64 rows(i) x 32 cols(jloc), stride 64B, 4KB
__device__ __forceinline__ int ps_off(int i, int j) {
  return (i << 6) + ((((j >> 3) ^ ((i >> 1) & 3)) << 4) | ((j & 7) << 1));
}

template <int UNROLL>
__device__ __forceinline__ void stage_x(const float* __restrict__ src, char* __restrict__ dst, int tid) {
  const float4* s4 = (const float4*)src;
#pragma unroll
  for (int kk = 0; kk < 8; kk += UNROLL) {
    float4 v[UNROLL];
#pragma unroll
    for (int u = 0; u < UNROLL; ++u) v[u] = s4[tid + ((kk + u) << 9)];
#pragma unroll
    for (int u = 0; u < UNROLL; ++u) {
      int f = tid + ((kk + u) << 9);
      int row = f >> 6;
      int col = (f & 63) << 2;
      bf16x4 p;
      p[0] = (bf16_t)v[u].x; p[1] = (bf16_t)v[u].y; p[2] = (bf16_t)v[u].z; p[3] = (bf16_t)v[u].w;
      *(bf16x4*)(dst + tile_off(row, col)) = p;
    }
  }
}

// y[0:64, cb:cb+32] = A(64x256 swizzled LDS) @ W(256x256 bf16 row-major)^T
__device__ __forceinline__ void gemm_tile(const char* __restrict__ sA, const bf16_t* __restrict__ W,
                                          int cb, int l15, int g, f32x4 acc[4][2]) {
#pragma unroll
  for (int kt = 0; kt < 8; ++kt) {
    bf16x8 a[4];
#pragma unroll
    for (int mt = 0; mt < 4; ++mt)
      a[mt] = *(const bf16x8*)(sA + tile_off(mt*16 + l15, kt*32 + g*8));
#pragma unroll
    for (int nt = 0; nt < 2; ++nt) {
      bf16x8 bw = *(const bf16x8*)(W + (cb + nt*16 + l15)*256 + kt*32 + g*8);
#pragma unroll
      for (int mt = 0; mt < 4; ++mt)
        acc[mt][nt] = __builtin_amdgcn_mfma_f32_16x16x32_bf16(a[mt], bw, acc[mt][nt], 0, 0, 0);
    }
  }
}

// dual-stream: two A-tiles x two W matrices -> two acc chains (2x the W-load MLP)
__device__ __forceinline__ void gemm_tile2(const char* __restrict__ sA, const char* __restrict__ sB,
                                           const bf16_t* __restrict__ W0, const bf16_t* __restrict__ W1,
                                           int cb, int l15, int g,
                                           f32x4 acc0[4][2], f32x4 acc1[4][2]) {
  const bf16_t* w0p = W0 + (cb + l15)*256 + g*8;
  const bf16_t* w1p = W1 + (cb + l15)*256 + g*8;
#pragma unroll
  for (int kt = 0; kt < 8; ++kt) {
    bf16x8 a0[4], a1[4];
#pragma unroll
    for (int mt = 0; mt < 4; ++mt) {
      a0[mt] = *(const bf16x8*)(sA + tile_off(mt*16 + l15, kt*32 + g*8));
      a1[mt] = *(const bf16x8*)(sB + tile_off(mt*16 + l15, kt*32 + g*8));
    }
#pragma unroll
    for (int nt = 0; nt < 2; ++nt) {
      bf16x8 bw0 = *(const bf16x8*)(w0p + nt*16*256 + kt*32);
      bf16x8 bw1 = *(const bf16x8*)(w1p + nt*16*256 + kt*32);
#pragma unroll
      for (int mt = 0; mt < 4; ++mt) {
        acc0[mt][nt] = __builtin_amdgcn_mfma_f32_16x16x32_bf16(a0[mt], bw0, acc0[mt][nt], 0, 0, 0);
        acc1[mt][nt] = __builtin_amdgcn_mfma_f32_16x16x32_bf16(a1[mt], bw1, acc1[mt][nt], 0, 0, 0);
      }
    }
  }
}

__global__ __launch_bounds__(512, 2)   // 256-reg budget: empirically no-spill
void chunk_attn_kernel(
    const float* __restrict__ qg, const float* __restrict__ kg, const float* __restrict__ vg,
    const float* __restrict__ maskg, const float* __restrict__ cmg,
    const float* __restrict__ bq, const float* __restrict__ bk, const float* __restrict__ bv,
    const float* __restrict__ bo, const float* __restrict__ rpbg,
    const bf16_t* __restrict__ Wb, float* __restrict__ outg) {
  extern __shared__ char sm[];
  char*  bufA  = sm + OFF_A;
  char*  bufB  = sm + OFF_B;
  float* sRpb  = (float*)(sm + OFF_RPB);    // transposed: [head][128] floats
  char*  sCmm  = sm + OFF_CMM;              // 64 x u64 row bitmasks (bit j: cm[i][j] == -100)

  const int b = blockIdx.x, tid = threadIdx.x;
  const int wave = tid >> 6, lane = tid & 63, l15 = lane & 15, g = lane >> 4;
  const int cb = wave << 5;             // head h = wave, feature base h*32
  char* scr = bufB + (wave << 12);      // 4KB/wave P^T scratch (overlays bufB post-B5)

  for (int i = tid; i < 1016; i += 512) sRpb[((i & 7) << 7) + (i >> 3)] = rpbg[i];
  { // pad-mask bits (wave 0) + chunk-mask bits (all waves, 8 rows each) via ballot
    if (wave == 0) {
      float mv = maskg[(b << 6) + lane];
      unsigned long long bm = __ballot(mv == 0.0f);
      if (lane == 0) *(unsigned long long*)(sm + OFF_PAD) = bm;
    }
    const float* cmb = cmg + ((size_t)(b & 127) << 12);
#pragma unroll
    for (int it = 0; it < 8; ++it) {
      int row = (wave << 3) + it;
      float cv = cmb[(row << 6) + lane];
      unsigned long long bm = __ballot(cv < -50.0f);
      if (lane == 0) *(unsigned long long*)(sCmm + (row << 3)) = bm;
    }
  }
  stage_x<4>(qg + (size_t)b*16384, bufA, tid);
  stage_x<4>(kg + (size_t)b*16384, bufB, tid);
  __syncthreads();                                        // B1

  { // q-proj || k-proj: dual W-load streams hide L2 latency
    f32x4 qacc[4][2] = {}, kacc[4][2] = {};
    gemm_tile2(bufA, bufB, Wb + 0*65536, Wb + 1*65536, cb, l15, g, qacc, kacc);
    __syncthreads();                                      // B2: X_q/X_k dead
    float bq0 = bq[cb+l15], bq1 = bq[cb+16+l15];
    float bk0 = bk[cb+l15], bk1 = bk[cb+16+l15];
#pragma unroll
    for (int mt = 0; mt < 4; ++mt)
#pragma unroll
      for (int nt = 0; nt < 2; ++nt)
#pragma unroll
        for (int r = 0; r < 4; ++r) {
          int row = mt*16 + g*4 + r, col = cb + nt*16 + l15;
          *(bf16_t*)(bufA + tile_off(row, col)) = (bf16_t)(qacc[mt][nt][r] + (nt ? bq1 : bq0));
          *(bf16_t*)(bufB + tile_off(row, col)) = (bf16_t)(kacc[mt][nt][r] + (nt ? bk1 : bk0));
        }
  }
  __asm__ volatile("s_waitcnt lgkmcnt(0)" ::: "memory");  // wave-private q/k RAW

  // scores^T: St[j][i] = sum_d K[j,d] Q[i,d]   (A=K, B=Q)
  f32x4 St[4][4];
  {
    bf16x8 ka[4], qb[4];
#pragma unroll
    for (int t = 0; t < 4; ++t) {
      ka[t] = *(const bf16x8*)(bufB + tile_off(t*16 + l15, cb + g*8));
      qb[t] = *(const bf16x8*)(bufA + tile_off(t*16 + l15, cb + g*8));
    }
    const f32x4 z = {};
#pragma unroll
    for (int mj = 0; mj < 4; ++mj)
#pragma unroll
      for (int ni = 0; ni < 4; ++ni)
        St[mj][ni] = __builtin_amdgcn_mfma_f32_16x16x32_bf16(ka[mj], qb[ni], z, 0, 0, 0);
  }

  // epilogue: j = mj*16+g*4+r (key pos), i = ni*16+l15 (query pos)
  const float* rpbw = sRpb + (wave << 7);
  unsigned long long padm = *(const unsigned long long*)(sm + OFF_PAD);
  unsigned int padl = (unsigned int)padm, padh = (unsigned int)(padm >> 32);
#pragma unroll
  for (int mj = 0; mj < 4; ++mj) {
    unsigned int pw = (mj >= 2) ? padh : padl;
#pragma unroll
    for (int ni = 0; ni < 4; ++ni) {
      int i = ni*16 + l15;
      unsigned long long cmm = *(const unsigned long long*)(sCmm + (i << 3));
      unsigned int cw = (mj >= 2) ? (unsigned int)(cmm >> 32) : (unsigned int)cmm;
#pragma unroll
      for (int r = 0; r < 4; ++r) {
        int j = mj*16 + g*4 + r;
        int sh = j & 31;
        float s1 = St[mj][ni][r] * 0.17677669529663689f + rpbw[i - j + 63];
        float base = ((pw >> sh) & 1u) ? -100.0f : s1;
        St[mj][ni][r] = ((cw >> sh) & 1u) ? base - 100.0f : base;
      }
    }
  }

  // softmax over j (16 in-lane + shfl_xor 16,32); P -> bf16 regs
  float rinv[4];
  bf16x4 pbf[4][4];
#pragma unroll
  for (int ni = 0; ni < 4; ++ni) {
    float m = -1e30f;
#pragma unroll
    for (int mj = 0; mj < 4; ++mj)
#pragma unroll
      for (int r = 0; r < 4; ++r) m = fmaxf(m, St[mj][ni][r]);
    m = fmaxf(m, __shfl_xor(m, 16));
    m = fmaxf(m, __shfl_xor(m, 32));
    float s = 0.0f;
#pragma unroll
    for (int mj = 0; mj < 4; ++mj)
#pragma unroll
      for (int r = 0; r < 4; ++r) {
        float p = __expf(St[mj][ni][r] - m);
        pbf[mj][ni][r] = (bf16_t)p;
        s += p;
      }
    s += __shfl_xor(s, 16);
    s += __shfl_xor(s, 32);
    rinv[ni] = 1.0f / s;
  }

  __syncthreads();                                        // B3: q/k globally dead
  stage_x<4>(vg + (size_t)b*16384, bufB, tid);
  __syncthreads();                                        // B4

  { // v projection -> vt (bufA, rows [cb,cb+32), transposed: row=feat, col=token)
    f32x4 vacc[4][2] = {};
    gemm_tile(bufB, Wb + 2*65536, cb, l15, g, vacc);
    float b0 = bv[cb+l15], b1 = bv[cb+16+l15];
#pragma unroll
    for (int nt = 0; nt < 2; ++nt)
#pragma unroll
      for (int mt = 0; mt < 4; ++mt) {
        bf16x4 p;
#pragma unroll
        for (int r = 0; r < 4; ++r) p[r] = (bf16_t)(vacc[mt][nt][r] + (nt ? b1 : b0));
        *(bf16x4*)(bufA + vt_off(cb + nt*16 + l15, mt*16 + g*4)) = p;
      }
  }
  __syncthreads();                                        // B5: X_v dead -> scratch ok

  // PV: x^T[d][i] = sum_j vt[d,j] P^T[j,i], two 32-j halves through 4KB scratch
  f32x4 Xa[2][4] = {};
#pragma unroll
  for (int h2 = 0; h2 < 2; ++h2) {
#pragma unroll
    for (int mj = 2*h2; mj < 2*h2 + 2; ++mj)
#pragma unroll
      for (int ni = 0; ni < 4; ++ni)
        *(bf16x4*)(scr + ps_off(ni*16 + l15, (mj & 1)*16 + g*4)) = pbf[mj][ni];
    __asm__ volatile("s_waitcnt lgkmcnt(0)" ::: "memory");
    bf16x8 va[2], pb[4];
#pragma unroll
    for (int mtd = 0; mtd < 2; ++mtd)
      va[mtd] = *(const bf16x8*)(bufA + vt_off(cb + mtd*16 + l15, h2*32 + g*8));
#pragma unroll
    for (int ni = 0; ni < 4; ++ni)
      pb[ni] = *(const bf16x8*)(scr + ps_off(ni*16 + l15, g*8));
#pragma unroll
    for (int mtd = 0; mtd < 2; ++mtd)
#pragma unroll
      for (int ni = 0; ni < 4; ++ni)
        Xa[mtd][ni] = __builtin_amdgcn_mfma_f32_16x16x32_bf16(va[mtd], pb[ni], Xa[mtd][ni], 0, 0, 0);
  }

  __syncthreads();                                        // B6: all PV done, bufB free
#pragma unroll
  for (int mtd = 0; mtd < 2; ++mtd)
#pragma unroll
    for (int ni = 0; ni < 4; ++ni)
#pragma unroll
      for (int r = 0; r < 4; ++r) {
        int dloc = mtd*16 + g*4 + r;    // C m-dim = feature d
        int i = ni*16 + l15;            // C n-dim = token i
        *(bf16_t*)(bufB + tile_off(i, cb + dloc)) = (bf16_t)(Xa[mtd][ni][r] * rinv[ni]);
      }
  __syncthreads();                                        // B7

  { // out = x @ Wo^T + bo
    f32x4 acc[4][2] = {};
    gemm_tile(bufB, Wb + 3*65536, cb, l15, g, acc);
    float b0 = bo[cb+l15], b1 = bo[cb+16+l15];
    float* ob = outg + (size_t)b * 16384;
#pragma unroll
    for (int mt = 0; mt < 4; ++mt)
#pragma unroll
      for (int nt = 0; nt < 2; ++nt)
#pragma unroll
        for (int r = 0; r < 4; ++r)
          ob[(mt*16 + g*4 + r)*256 + cb + nt*16 + l15] = acc[mt][nt][r] + (nt ? b1 : b0);
  }
}

__global__ void cvt_weights(const float* __restrict__ Wq, const float* __restrict__ Wk,
                            const float* __restrict__ Wv, const float* __restrict__ Wo,
                            bf16_t* __restrict__ dst) {
  int idx = blockIdx.x * 256 + threadIdx.x;
  int which = idx >> 14;
  int off = idx & 16383;
  const float* src = (which == 0) ? Wq : (which == 1) ? Wk : (which == 2) ? Wv : Wo;
  float4 v = ((const float4*)src)[off];
  bf16x4 p;
  p[0] = (bf16_t)v.x; p[1] = (bf16_t)v.y; p[2] = (bf16_t)v.z; p[3] = (bf16_t)v.w;
  *(bf16x4*)(dst + which*65536 + off*4) = p;
}

extern "C" void kernel_launch(void* const* d_in, const int* in_sizes, int n_in,
                              void* d_out, int out_size, void* d_ws, size_t ws_size,
                              hipStream_t stream) {
  (void)in_sizes; (void)n_in; (void)out_size; (void)ws_size;
  const float* qg  = (const float*)d_in[0];
  const float* kg  = (const float*)d_in[1];
  const float* vg  = (const float*)d_in[2];
  const float* mg  = (const float*)d_in[3];
  const float* cmg = (const float*)d_in[4];
  const float* Wq  = (const float*)d_in[5];
  const float* bq  = (const float*)d_in[6];
  const float* Wk  = (const float*)d_in[7];
  const float* bk  = (const float*)d_in[8];
  const float* Wv  = (const float*)d_in[9];
  const float* bv  = (const float*)d_in[10];
  const float* Wo  = (const float*)d_in[11];
  const float* bo  = (const float*)d_in[12];
  const float* rpb = (const float*)d_in[13];
  bf16_t* Wb = (bf16_t*)d_ws;           // 4 * 65536 bf16 = 512 KB
  float* outg = (float*)d_out;

  hipFuncSetAttribute(reinterpret_cast<const void*>(chunk_attn_kernel),
                      hipFuncAttributeMaxDynamicSharedMemorySize, SMEM_BYTES);
  cvt_weights<<<256, 256, 0, stream>>>(Wq, Wk, Wv, Wo, Wb);
  chunk_attn_kernel<<<2048, 512, SMEM_BYTES, stream>>>(qg, kg, vg, mg, cmg,
      bq, bk, bv, bo, rpb, Wb, outg);
}